// Round 2
// baseline (788.562 us; speedup 1.0000x reference)
//
#include <hip/hip_runtime.h>
#include <stdint.h>

typedef short bf16x8 __attribute__((ext_vector_type(8)));
typedef float f32x4 __attribute__((ext_vector_type(4)));

#define BATCH 8192
#define EMBED 8192
#define U0    1024
#define U1    256
#define NHEAD 6

// ---------- helpers ----------
__device__ __forceinline__ unsigned short f2bf(float f) {
  union { float f; unsigned int u; } v; v.f = f;
  unsigned int u = v.u;
  unsigned int r = u + 0x7FFFu + ((u >> 16) & 1u);  // RNE
  return (unsigned short)(r >> 16);
}
__device__ __forceinline__ void async_copy16(const void* g, void* l) {
  __builtin_amdgcn_global_load_lds((const __attribute__((address_space(1))) void*)g,
                                   (__attribute__((address_space(3))) void*)l, 16, 0, 0);
}

// ---------- kernel 1: transpose + convert: in[R][C] fp32 -> out[C][R] bf16 ----------
__global__ void transpose_cvt_kernel(const float* __restrict__ in, unsigned short* __restrict__ out,
                                     int R, int C, long in_z, long out_z) {
  __shared__ unsigned short tile[64][65];
  const float* inp = in + (long)blockIdx.z * in_z;
  unsigned short* outp = out + (long)blockIdx.z * out_z;
  int r0 = blockIdx.x * 64;
  int c0 = blockIdx.y * 64;
  int lc = threadIdx.x & 63;
  int lr = threadIdx.x >> 6;  // 0..3
#pragma unroll
  for (int i = 0; i < 16; i++) {
    int r = lr + i * 4;
    tile[r][lc] = f2bf(inp[(long)(r0 + r) * C + (c0 + lc)]);
  }
  __syncthreads();
#pragma unroll
  for (int i = 0; i < 16; i++) {
    int c = lr + i * 4;
    outp[(long)(c0 + c) * R + (r0 + lc)] = tile[lc][c];
  }
}

// ---------- kernel 2: bucket rows by command (single block) ----------
__global__ void bucket_kernel(const int* __restrict__ cmd, int* __restrict__ idxlist,
                              int* __restrict__ meta) {
  __shared__ int cnt[NHEAD], cur[NHEAD], off[NHEAD + 1];
  int tid = threadIdx.x;
  if (tid < NHEAD) cnt[tid] = 0;
  __syncthreads();
  for (int b = tid; b < BATCH; b += blockDim.x) atomicAdd(&cnt[cmd[b]], 1);
  __syncthreads();
  if (tid == 0) {
    int s = 0;
    for (int h2 = 0; h2 < NHEAD; h2++) { off[h2] = s; s += cnt[h2]; }
    off[NHEAD] = s;
  }
  __syncthreads();
  if (tid < NHEAD) cur[tid] = off[tid];
  if (tid <= NHEAD) meta[tid] = off[tid];
  __syncthreads();
  for (int b = tid; b < BATCH; b += blockDim.x) {
    int p = atomicAdd(&cur[cmd[b]], 1);
    idxlist[p] = b;
  }
}

// ---------- kernel 3: GEMM (split-K=2)  P[kh] = x[:, kh*4096:(kh+1)*4096] @ fc_W[same rows] ----------
// A = x fp32 (converted to bf16 in-register during staging). B = wt[1024][8192] bf16 (fc_W^T).
// 128x128 tile, BK=64, 4 waves 2x2, each wave 64x64 (4x4 of 16x16x32 MFMA).
// Grid 1024 = 2 k-halves x 64 by x 8 bx. XCD-bijective swizzle: 1024 % 8 == 0;
// XCD c owns by in [8c,8c+8) (both k-halves) -> A panels L2-resident per XCD.
// Output: fp32 partials, summed+bias+relu in reduce_kernel.
__global__ __launch_bounds__(256) void gemm_kernel(const float* __restrict__ x,
                                                   const unsigned short* __restrict__ wt,
                                                   float* __restrict__ pbuf) {
  __shared__ uint4 As[1024];  // 16 KB
  __shared__ uint4 Bs[1024];  // 16 KB
  int tid  = threadIdx.x;
  int lane = tid & 63;
  int wave = tid >> 6;
  int wm = wave >> 1, wn = wave & 1;

  int f = blockIdx.x;        // 0..1023
  int xcd = f & 7;
  int idx = f >> 3;          // 0..127
  int kh  = idx >> 6;        // 0..1
  int sub = idx & 63;        // 0..63
  int by = xcd * 8 + (sub >> 3);
  int bx = sub & 7;
  int m0 = by * 128;
  int n0 = bx * 128;
  int l15 = lane & 15, lq = lane >> 4;

  // staging sources: combo c = (cwm*2+cks)*4+cmi ; this wave handles c = wave*4..wave*4+3
  long asrc[4], bsrc[4];
#pragma unroll
  for (int j = 0; j < 4; j++) {
    int c = wave * 4 + j;
    int cwm = c >> 3, cks = (c >> 2) & 1, cmi = c & 3;
    int kofs = cks * 32 + lq * 8;
    asrc[j] = (long)(m0 + cwm * 64 + cmi * 16 + l15) * EMBED + kofs;
    bsrc[j] = (long)(n0 + cwm * 64 + cmi * 16 + l15) * EMBED + kofs;
  }

  f32x4 zero = {0.f, 0.f, 0.f, 0.f};
  f32x4 acc[4][4];
#pragma unroll
  for (int mi = 0; mi < 4; mi++)
#pragma unroll
    for (int ni = 0; ni < 4; ni++) acc[mi][ni] = zero;

  const int kbeg = kh * 4096;
  for (int k0 = kbeg; k0 < kbeg + 4096; k0 += 64) {
    __syncthreads();
    // A loads first (fp32 -> regs): the cvt's vmcnt wait then leaves B copies
    // (issued after, retired after) still in flight.
    float4 a0[4], a1[4];
#pragma unroll
    for (int j = 0; j < 4; j++) {
      const float* p = x + asrc[j] + k0;
      a0[j] = *(const float4*)p;
      a1[j] = *(const float4*)(p + 4);
    }
#pragma unroll
    for (int j = 0; j < 4; j++) {
      int c = wave * 4 + j;
      async_copy16(wt + bsrc[j] + k0, &Bs[c * 64 + lane]);
    }
#pragma unroll
    for (int j = 0; j < 4; j++) {
      int c = wave * 4 + j;
      unsigned int q0, q1, q2, q3;
      asm("v_cvt_pk_bf16_f32 %0, %1, %2" : "=v"(q0) : "v"(a0[j].x), "v"(a0[j].y));
      asm("v_cvt_pk_bf16_f32 %0, %1, %2" : "=v"(q1) : "v"(a0[j].z), "v"(a0[j].w));
      asm("v_cvt_pk_bf16_f32 %0, %1, %2" : "=v"(q2) : "v"(a1[j].x), "v"(a1[j].y));
      asm("v_cvt_pk_bf16_f32 %0, %1, %2" : "=v"(q3) : "v"(a1[j].z), "v"(a1[j].w));
      uint4 r; r.x = q0; r.y = q1; r.z = q2; r.w = q3;
      As[c * 64 + lane] = r;
    }
    __syncthreads();
#pragma unroll
    for (int ks = 0; ks < 2; ks++) {
      bf16x8 af[4], bfr[4];
#pragma unroll
      for (int mi = 0; mi < 4; mi++) af[mi] = *(const bf16x8*)&As[((wm * 2 + ks) * 4 + mi) * 64 + lane];
#pragma unroll
      for (int ni = 0; ni < 4; ni++) bfr[ni] = *(const bf16x8*)&Bs[((wn * 2 + ks) * 4 + ni) * 64 + lane];
#pragma unroll
      for (int mi = 0; mi < 4; mi++)
#pragma unroll
        for (int ni = 0; ni < 4; ni++)
          acc[mi][ni] = __builtin_amdgcn_mfma_f32_16x16x32_bf16(af[mi], bfr[ni], acc[mi][ni], 0, 0, 0);
    }
  }

  // store fp32 partials.  D: col=lane&15, row=(lane>>4)*4+reg
  float* p = pbuf + (long)kh * (8192L * 1024);
#pragma unroll
  for (int ni = 0; ni < 4; ni++) {
    int col = n0 + wn * 64 + ni * 16 + l15;
#pragma unroll
    for (int mi = 0; mi < 4; mi++) {
      int rbase = m0 + wm * 64 + mi * 16 + lq * 4;
#pragma unroll
      for (int r = 0; r < 4; r++) {
        p[(long)(rbase + r) * U0 + col] = acc[mi][ni][r];
      }
    }
  }
}

// ---------- kernel 4: reduce partials + bias + relu -> h bf16 ----------
__global__ __launch_bounds__(256) void reduce_kernel(const float* __restrict__ pbuf,
                                                     const float* __restrict__ fc_b,
                                                     unsigned short* __restrict__ h) {
  long i = ((long)blockIdx.x * 256 + threadIdx.x) * 8;
  const float* P1 = pbuf + 8192L * 1024;
  float4 a0 = *(const float4*)(pbuf + i);
  float4 a1 = *(const float4*)(pbuf + i + 4);
  float4 c0 = *(const float4*)(P1 + i);
  float4 c1 = *(const float4*)(P1 + i + 4);
  int cb = (int)(i & (U0 - 1));
  float4 b0 = *(const float4*)(fc_b + cb);
  float4 b1 = *(const float4*)(fc_b + cb + 4);
  float v[8];
  v[0] = a0.x + c0.x + b0.x; v[1] = a0.y + c0.y + b0.y;
  v[2] = a0.z + c0.z + b0.z; v[3] = a0.w + c0.w + b0.w;
  v[4] = a1.x + c1.x + b1.x; v[5] = a1.y + c1.y + b1.y;
  v[6] = a1.z + c1.z + b1.z; v[7] = a1.w + c1.w + b1.w;
  uint4 r;
  unsigned int q[4];
#pragma unroll
  for (int j = 0; j < 4; j++) {
    float lo = v[2 * j]     > 0.f ? v[2 * j]     : 0.f;
    float hi = v[2 * j + 1] > 0.f ? v[2 * j + 1] : 0.f;
    q[j] = (unsigned int)f2bf(lo) | ((unsigned int)f2bf(hi) << 16);
  }
  r.x = q[0]; r.y = q[1]; r.z = q[2]; r.w = q[3];
  *(uint4*)(h + i) = r;
}

// ---------- kernel 5: selected-head MLP + epilogue ----------
// grid (256, 6): y = head, x = 32-row tile of that head's bucket. 4 waves over N=256.
__global__ __launch_bounds__(256) void head_kernel(const unsigned short* __restrict__ h,
                                                   const unsigned short* __restrict__ w1t,
                                                   const float* __restrict__ W1,
                                                   const float* __restrict__ b1,
                                                   const float* __restrict__ W2,
                                                   const float* __restrict__ b2,
                                                   const float* __restrict__ ego,
                                                   const int* __restrict__ idxlist,
                                                   const int* __restrict__ meta,
                                                   float* __restrict__ out) {
  int hd = blockIdx.y;
  int off = meta[hd];
  int cnt = meta[hd + 1] - off;
  int t0 = blockIdx.x * 32;
  if (t0 >= cnt) return;

  __shared__ int ridx[32];
  __shared__ float h1s[32][257];
  __shared__ float w2s[1024];  // W2[hd] preloaded: [256][4]
  int tid = threadIdx.x;
  if (tid < 32) {
    int i = t0 + tid;
    ridx[tid] = idxlist[off + (i < cnt ? i : 0)];
  }
  *(float4*)&w2s[tid * 4] = *(const float4*)(W2 + (long)hd * 1024 + tid * 4);
  __syncthreads();

  int lane = tid & 63, wave = tid >> 6;
  int l15 = lane & 15, lq = lane >> 4;

  long abase[2];
#pragma unroll
  for (int mi = 0; mi < 2; mi++) abase[mi] = (long)ridx[mi * 16 + l15] * U0 + lq * 8;
  long bbase[4];
#pragma unroll
  for (int ni = 0; ni < 4; ni++)
    bbase[ni] = (long)(hd * 256 + wave * 64 + ni * 16 + l15) * 1024 + lq * 8;

  f32x4 zero = {0.f, 0.f, 0.f, 0.f};
  f32x4 acc[2][4];
#pragma unroll
  for (int mi = 0; mi < 2; mi++)
#pragma unroll
    for (int ni = 0; ni < 4; ni++) acc[mi][ni] = zero;

#pragma unroll 2
  for (int k0 = 0; k0 < 1024; k0 += 32) {
    bf16x8 af[2], bfr[4];
#pragma unroll
    for (int mi = 0; mi < 2; mi++) af[mi] = *(const bf16x8*)(h + abase[mi] + k0);
#pragma unroll
    for (int ni = 0; ni < 4; ni++) bfr[ni] = *(const bf16x8*)(w1t + bbase[ni] + k0);
#pragma unroll
    for (int mi = 0; mi < 2; mi++)
#pragma unroll
      for (int ni = 0; ni < 4; ni++)
        acc[mi][ni] = __builtin_amdgcn_mfma_f32_16x16x32_bf16(af[mi], bfr[ni], acc[mi][ni], 0, 0, 0);
  }

  // ego contribution (fp32 exact) + bias + relu -> LDS
  const float* W1e = W1 + (long)hd * 1027 * 256 + (long)1024 * 256;  // rows 1024..1026
#pragma unroll
  for (int mi = 0; mi < 2; mi++)
#pragma unroll
    for (int r = 0; r < 4; r++) {
      int rl = mi * 16 + lq * 4 + r;
      int b = ridx[rl];
      float e0 = ego[b * 3 + 0], e1 = ego[b * 3 + 1], e2 = ego[b * 3 + 2];
#pragma unroll
      for (int ni = 0; ni < 4; ni++) {
        int col = wave * 64 + ni * 16 + l15;
        float v = acc[mi][ni][r] + b1[hd * 256 + col]
                + e0 * W1e[col] + e1 * W1e[256 + col] + e2 * W1e[512 + col];
        h1s[rl][col] = v > 0.f ? v : 0.f;
      }
    }
  __syncthreads();

  // h2 = h1 @ W2[hd] + b2[hd]; tanh/softplus epilogue; scatter by original row
  if (tid < 128) {
    int t = tid >> 2, o2 = tid & 3;
    if (t0 + t < cnt) {
      float s0 = 0.f, s1 = 0.f, s2 = 0.f, s3 = 0.f;
#pragma unroll 4
      for (int i = 0; i < 256; i += 4) {
        s0 += h1s[t][i + 0] * w2s[(i + 0) * 4 + o2];
        s1 += h1s[t][i + 1] * w2s[(i + 1) * 4 + o2];
        s2 += h1s[t][i + 2] * w2s[(i + 2) * 4 + o2];
        s3 += h1s[t][i + 3] * w2s[(i + 3) * 4 + o2];
      }
      float sum = b2[hd * 4 + o2] + ((s0 + s1) + (s2 + s3));
      int b = ridx[t];
      float res;
      if (o2 < 2) {
        res = 5.0f * tanhf(sum * 0.2f);
      } else {
        float z = sum + 4.99323838f;  // log(exp(5)-1)
        res = (z > 20.f ? z : log1pf(expf(z))) + 1e-4f;
      }
      out[b * 4 + o2] = res;
    }
  }
}

// ---------- launcher ----------
extern "C" void kernel_launch(void* const* d_in, const int* in_sizes, int n_in,
                              void* d_out, int out_size, void* d_ws, size_t ws_size,
                              hipStream_t stream) {
  const float* x   = (const float*)d_in[0];
  const int*   cmd = (const int*)d_in[1];
  const float* ego = (const float*)d_in[2];
  const float* fcW = (const float*)d_in[3];
  const float* fcb = (const float*)d_in[4];
  const float* W1  = (const float*)d_in[5];
  const float* b1  = (const float*)d_in[6];
  const float* W2  = (const float*)d_in[7];
  const float* b2  = (const float*)d_in[8];
  float* out = (float*)d_out;

  char* ws = (char*)d_ws;
  float* pbuf          = (float*)(ws);                          // 64 MB  fp32 partials [2][8192][1024]
  unsigned short* wt   = (unsigned short*)(ws + 67108864);      // 16 MB  fc_W^T bf16
  unsigned short* hbuf = (unsigned short*)(ws + 83886080);      // 16 MB  h bf16
  unsigned short* w1t  = (unsigned short*)(ws + 100663296);     // 3 MB   W1^T bf16
  int* idxlist         = (int*)(ws + 103809024);                // 32 KB
  int* meta            = (int*)(ws + 103841792);                // 7 ints

  hipLaunchKernelGGL(transpose_cvt_kernel, dim3(128, 16, 1), dim3(256), 0, stream,
                     fcW, wt, 8192, 1024, 0L, 0L);
  hipLaunchKernelGGL(transpose_cvt_kernel, dim3(16, 4, 6), dim3(256), 0, stream,
                     W1, w1t, 1024, 256, (long)1027 * 256, (long)256 * 1024);
  hipLaunchKernelGGL(bucket_kernel, dim3(1), dim3(1024), 0, stream, cmd, idxlist, meta);
  hipLaunchKernelGGL(gemm_kernel, dim3(1024), dim3(256), 0, stream, x, wt, pbuf);
  hipLaunchKernelGGL(reduce_kernel, dim3(4096), dim3(256), 0, stream, pbuf, fcb, hbuf);
  hipLaunchKernelGGL(head_kernel, dim3(256, 6), dim3(256), 0, stream,
                     hbuf, w1t, W1, b1, W2, b2, ego, idxlist, meta, out);
}

// Round 3
// 755.291 us; speedup vs baseline: 1.0441x; 1.0441x over previous
//
#include <hip/hip_runtime.h>
#include <stdint.h>

typedef short bf16x8 __attribute__((ext_vector_type(8)));
typedef float f32x4 __attribute__((ext_vector_type(4)));

#define BATCH 8192
#define EMBED 8192
#define U0    1024
#define U1    256
#define NHEAD 6

// ---------- helpers ----------
__device__ __forceinline__ unsigned short f2bf(float f) {
  union { float f; unsigned int u; } v; v.f = f;
  unsigned int u = v.u;
  unsigned int r = u + 0x7FFFu + ((u >> 16) & 1u);  // RNE
  return (unsigned short)(r >> 16);
}
__device__ __forceinline__ unsigned int pk2(float lo, float hi) {
  return (unsigned int)f2bf(lo) | ((unsigned int)f2bf(hi) << 16);
}
__device__ __forceinline__ void async_copy16(const void* g, void* l) {
  __builtin_amdgcn_global_load_lds((const __attribute__((address_space(1))) void*)g,
                                   (__attribute__((address_space(3))) void*)l, 16, 0, 0);
}

// ---------- kernel 1: x fp32 -> bf16 (row-major, K contiguous) ----------
__global__ void cvt_x_kernel(const float* __restrict__ x, unsigned short* __restrict__ xb) {
  long i = ((long)blockIdx.x * 256 + threadIdx.x) * 8;
  float4 a = *(const float4*)(x + i);
  float4 b = *(const float4*)(x + i + 4);
  uint4 r;
  r.x = pk2(a.x, a.y); r.y = pk2(a.z, a.w);
  r.z = pk2(b.x, b.y); r.w = pk2(b.z, b.w);
  *(uint4*)(xb + i) = r;
}

// ---------- kernel 2: transpose + convert: in[R][C] fp32 -> out[C][R] bf16 ----------
__global__ void transpose_cvt_kernel(const float* __restrict__ in, unsigned short* __restrict__ out,
                                     int R, int C, long in_z, long out_z) {
  __shared__ unsigned short tile[64][65];
  const float* inp = in + (long)blockIdx.z * in_z;
  unsigned short* outp = out + (long)blockIdx.z * out_z;
  int r0 = blockIdx.x * 64;
  int c0 = blockIdx.y * 64;
  int lc = threadIdx.x & 63;
  int lr = threadIdx.x >> 6;  // 0..3
#pragma unroll
  for (int i = 0; i < 16; i++) {
    int r = lr + i * 4;
    tile[r][lc] = f2bf(inp[(long)(r0 + r) * C + (c0 + lc)]);
  }
  __syncthreads();
#pragma unroll
  for (int i = 0; i < 16; i++) {
    int c = lr + i * 4;
    outp[(long)(c0 + c) * R + (r0 + lc)] = tile[lc][c];
  }
}

// ---------- kernel 3: bucket rows by command (single block, ballot-aggregated) ----------
// Old version: 16384 LDS atomics on 6 addresses (worst-case serialization).
// New: per-wave ballot -> popcount -> 1 atomic per wave per head; scatter position
// via mask-prefix popcount. Order within a bucket is irrelevant (final scatter is by
// original row index).
__global__ void bucket_kernel(const int* __restrict__ cmd, int* __restrict__ idxlist,
                              int* __restrict__ meta) {
  __shared__ int cnt[NHEAD], cur[NHEAD], off[NHEAD + 1];
  int tid = threadIdx.x;            // 1024 threads = 16 waves
  int lane = tid & 63, wave = tid >> 6;
  if (tid < NHEAD) cnt[tid] = 0;
  __syncthreads();
  for (int base = wave * 64; base < BATCH; base += 1024) {
    int c = cmd[base + lane];
#pragma unroll
    for (int h2 = 0; h2 < NHEAD; h2++) {
      unsigned long long m = __ballot(c == h2);
      if (lane == 0 && m) atomicAdd(&cnt[h2], __popcll(m));
    }
  }
  __syncthreads();
  if (tid == 0) {
    int s = 0;
    for (int h2 = 0; h2 < NHEAD; h2++) { off[h2] = s; s += cnt[h2]; }
    off[NHEAD] = s;
  }
  __syncthreads();
  if (tid < NHEAD) cur[tid] = off[tid];
  if (tid <= NHEAD) meta[tid] = off[tid];
  __syncthreads();
  for (int base = wave * 64; base < BATCH; base += 1024) {
    int b = base + lane;
    int c = cmd[b];
    int pos = 0;
#pragma unroll
    for (int h2 = 0; h2 < NHEAD; h2++) {
      unsigned long long m = __ballot(c == h2);
      if (m) {                       // wave-uniform branch (ballot result)
        int leader = (int)(__ffsll((unsigned long long)m) - 1);
        int wbase = 0;
        if (lane == leader) wbase = atomicAdd(&cur[h2], __popcll(m));
        wbase = __shfl(wbase, leader);
        if (c == h2) pos = wbase + __popcll(m & ((1ULL << lane) - 1ULL));
      }
    }
    idxlist[pos] = b;
  }
}

// ---------- kernel 4: GEMM  h = relu(xb @ fc_W + fc_b), bf16 MFMA ----------
// A = xb[8192][8192] bf16 (M x K); B = wt[1024][8192] bf16 (N x K = fc_W^T).
// 128x128 tile, BK=64, 8 waves (512 thr) in 4x2, wave-tile 32x64 (2x4 of 16x16x32).
// Both operands staged via global_load_lds width=16 in fragment order (m97 structure);
// 8 waves -> 16 waves/CU at 2 blocks/CU. Staging:MFMA inst ratio 1:4 (= m97).
// XCD-bijective swizzle: 512 % 8 == 0; XCD c owns by in [8c,8c+8), bx fastest.
__global__ __launch_bounds__(512) void gemm_kernel(const unsigned short* __restrict__ xb,
                                                   const unsigned short* __restrict__ wt,
                                                   const float* __restrict__ fc_b,
                                                   unsigned short* __restrict__ h) {
  __shared__ uint4 As[1024];  // 16 KB: slot ((wm*2+ks)*2+mi)*64 + lane
  __shared__ uint4 Bs[1024];  // 16 KB: slot ((wn*2+ks)*4+ni)*64 + lane
  int tid  = threadIdx.x;
  int lane = tid & 63;
  int wave = tid >> 6;        // 0..7
  int wm = wave >> 1;         // 0..3
  int wn = wave & 1;          // 0..1

  int f = blockIdx.x;         // 0..511
  int xcd = f & 7;
  int idx = f >> 3;           // 0..63
  int by = xcd * 8 + (idx >> 3);
  int bx = idx & 7;
  int m0 = by * 128;
  int n0 = bx * 128;
  int l15 = lane & 15, lq = lane >> 4;

  // staging: 2048 slots over 512 lanes = 2 A-copies + 2 B-copies per lane.
  // wave w stages A slot-groups {2w, 2w+1} and B slot-groups {2w, 2w+1}.
  long asrc[2], bsrc[2];
#pragma unroll
  for (int j = 0; j < 2; j++) {
    int ca = wave * 2 + j;                 // 0..15 = (cwm*2+cks)*2+cmi
    int cwm = ca >> 2, cka = (ca >> 1) & 1, cmi = ca & 1;
    asrc[j] = (long)(m0 + cwm * 32 + cmi * 16 + l15) * EMBED + cka * 32 + lq * 8;
    int cb = wave * 2 + j;                 // 0..15 = (cwn*2+cks)*4+cni
    int cwn = cb >> 3, ckb = (cb >> 2) & 1, cni = cb & 3;
    bsrc[j] = (long)(n0 + cwn * 64 + cni * 16 + l15) * EMBED + ckb * 32 + lq * 8;
  }

  f32x4 zero = {0.f, 0.f, 0.f, 0.f};
  f32x4 acc[2][4];
#pragma unroll
  for (int mi = 0; mi < 2; mi++)
#pragma unroll
    for (int ni = 0; ni < 4; ni++) acc[mi][ni] = zero;

  for (int k0 = 0; k0 < EMBED; k0 += 64) {
    __syncthreads();
#pragma unroll
    for (int j = 0; j < 2; j++) {
      int c = wave * 2 + j;
      async_copy16(xb + asrc[j] + k0, &As[c * 64 + lane]);
      async_copy16(wt + bsrc[j] + k0, &Bs[c * 64 + lane]);
    }
    __syncthreads();
#pragma unroll
    for (int ks = 0; ks < 2; ks++) {
      bf16x8 af[2], bfr[4];
#pragma unroll
      for (int mi = 0; mi < 2; mi++) af[mi] = *(const bf16x8*)&As[((wm * 2 + ks) * 2 + mi) * 64 + lane];
#pragma unroll
      for (int ni = 0; ni < 4; ni++) bfr[ni] = *(const bf16x8*)&Bs[((wn * 2 + ks) * 4 + ni) * 64 + lane];
#pragma unroll
      for (int mi = 0; mi < 2; mi++)
#pragma unroll
        for (int ni = 0; ni < 4; ni++)
          acc[mi][ni] = __builtin_amdgcn_mfma_f32_16x16x32_bf16(af[mi], bfr[ni], acc[mi][ni], 0, 0, 0);
    }
  }

  // epilogue: +bias, relu, store bf16.  D: col=lane&15, row=(lane>>4)*4+reg
#pragma unroll
  for (int ni = 0; ni < 4; ni++) {
    int col = n0 + wn * 64 + ni * 16 + l15;
    float bias = fc_b[col];
#pragma unroll
    for (int mi = 0; mi < 2; mi++) {
      int rbase = m0 + wm * 32 + mi * 16 + lq * 4;
#pragma unroll
      for (int r = 0; r < 4; r++) {
        float v = acc[mi][ni][r] + bias;
        v = v > 0.f ? v : 0.f;
        h[(long)(rbase + r) * U0 + col] = f2bf(v);
      }
    }
  }
}

// ---------- kernel 5: selected-head MLP + epilogue ----------
// grid (256, 6): y = head, x = 32-row tile of that head's bucket. 4 waves over N=256.
__global__ __launch_bounds__(256) void head_kernel(const unsigned short* __restrict__ h,
                                                   const unsigned short* __restrict__ w1t,
                                                   const float* __restrict__ W1,
                                                   const float* __restrict__ b1,
                                                   const float* __restrict__ W2,
                                                   const float* __restrict__ b2,
                                                   const float* __restrict__ ego,
                                                   const int* __restrict__ idxlist,
                                                   const int* __restrict__ meta,
                                                   float* __restrict__ out) {
  int hd = blockIdx.y;
  int off = meta[hd];
  int cnt = meta[hd + 1] - off;
  int t0 = blockIdx.x * 32;
  if (t0 >= cnt) return;

  __shared__ int ridx[32];
  __shared__ float h1s[32][257];
  __shared__ float w2s[1024];  // W2[hd] preloaded: [256][4]
  int tid = threadIdx.x;
  if (tid < 32) {
    int i = t0 + tid;
    ridx[tid] = idxlist[off + (i < cnt ? i : 0)];
  }
  *(float4*)&w2s[tid * 4] = *(const float4*)(W2 + (long)hd * 1024 + tid * 4);
  __syncthreads();

  int lane = tid & 63, wave = tid >> 6;
  int l15 = lane & 15, lq = lane >> 4;

  long abase[2];
#pragma unroll
  for (int mi = 0; mi < 2; mi++) abase[mi] = (long)ridx[mi * 16 + l15] * U0 + lq * 8;
  long bbase[4];
#pragma unroll
  for (int ni = 0; ni < 4; ni++)
    bbase[ni] = (long)(hd * 256 + wave * 64 + ni * 16 + l15) * 1024 + lq * 8;

  f32x4 zero = {0.f, 0.f, 0.f, 0.f};
  f32x4 acc[2][4];
#pragma unroll
  for (int mi = 0; mi < 2; mi++)
#pragma unroll
    for (int ni = 0; ni < 4; ni++) acc[mi][ni] = zero;

#pragma unroll 2
  for (int k0 = 0; k0 < 1024; k0 += 32) {
    bf16x8 af[2], bfr[4];
#pragma unroll
    for (int mi = 0; mi < 2; mi++) af[mi] = *(const bf16x8*)(h + abase[mi] + k0);
#pragma unroll
    for (int ni = 0; ni < 4; ni++) bfr[ni] = *(const bf16x8*)(w1t + bbase[ni] + k0);
#pragma unroll
    for (int mi = 0; mi < 2; mi++)
#pragma unroll
      for (int ni = 0; ni < 4; ni++)
        acc[mi][ni] = __builtin_amdgcn_mfma_f32_16x16x32_bf16(af[mi], bfr[ni], acc[mi][ni], 0, 0, 0);
  }

  // ego contribution (fp32 exact) + bias + relu -> LDS
  const float* W1e = W1 + (long)hd * 1027 * 256 + (long)1024 * 256;  // rows 1024..1026
#pragma unroll
  for (int mi = 0; mi < 2; mi++)
#pragma unroll
    for (int r = 0; r < 4; r++) {
      int rl = mi * 16 + lq * 4 + r;
      int b = ridx[rl];
      float e0 = ego[b * 3 + 0], e1 = ego[b * 3 + 1], e2 = ego[b * 3 + 2];
#pragma unroll
      for (int ni = 0; ni < 4; ni++) {
        int col = wave * 64 + ni * 16 + l15;
        float v = acc[mi][ni][r] + b1[hd * 256 + col]
                + e0 * W1e[col] + e1 * W1e[256 + col] + e2 * W1e[512 + col];
        h1s[rl][col] = v > 0.f ? v : 0.f;
      }
    }
  __syncthreads();

  // h2 = h1 @ W2[hd] + b2[hd]; tanh/softplus epilogue; scatter by original row
  if (tid < 128) {
    int t = tid >> 2, o2 = tid & 3;
    if (t0 + t < cnt) {
      float s0 = 0.f, s1 = 0.f, s2 = 0.f, s3 = 0.f;
#pragma unroll 4
      for (int i = 0; i < 256; i += 4) {
        s0 += h1s[t][i + 0] * w2s[(i + 0) * 4 + o2];
        s1 += h1s[t][i + 1] * w2s[(i + 1) * 4 + o2];
        s2 += h1s[t][i + 2] * w2s[(i + 2) * 4 + o2];
        s3 += h1s[t][i + 3] * w2s[(i + 3) * 4 + o2];
      }
      float sum = b2[hd * 4 + o2] + ((s0 + s1) + (s2 + s3));
      int b = ridx[t];
      float res;
      if (o2 < 2) {
        res = 5.0f * tanhf(sum * 0.2f);
      } else {
        float z = sum + 4.99323838f;  // log(exp(5)-1)
        res = (z > 20.f ? z : log1pf(expf(z))) + 1e-4f;
      }
      out[b * 4 + o2] = res;
    }
  }
}

// ---------- launcher ----------
extern "C" void kernel_launch(void* const* d_in, const int* in_sizes, int n_in,
                              void* d_out, int out_size, void* d_ws, size_t ws_size,
                              hipStream_t stream) {
  const float* x   = (const float*)d_in[0];
  const int*   cmd = (const int*)d_in[1];
  const float* ego = (const float*)d_in[2];
  const float* fcW = (const float*)d_in[3];
  const float* fcb = (const float*)d_in[4];
  const float* W1  = (const float*)d_in[5];
  const float* b1  = (const float*)d_in[6];
  const float* W2  = (const float*)d_in[7];
  const float* b2  = (const float*)d_in[8];
  float* out = (float*)d_out;

  char* ws = (char*)d_ws;
  unsigned short* xb   = (unsigned short*)(ws);                 // 128 MB  x bf16
  unsigned short* wt   = (unsigned short*)(ws + 134217728);     // 16 MB   fc_W^T bf16
  unsigned short* hbuf = (unsigned short*)(ws + 150994944);     // 16 MB   h bf16
  unsigned short* w1t  = (unsigned short*)(ws + 167772160);     // 3 MB    W1^T bf16
  int* idxlist         = (int*)(ws + 170917888);                // 32 KB
  int* meta            = (int*)(ws + 170950656);                // 7 ints

  hipLaunchKernelGGL(cvt_x_kernel, dim3(32768), dim3(256), 0, stream, x, xb);
  hipLaunchKernelGGL(transpose_cvt_kernel, dim3(128, 16, 1), dim3(256), 0, stream,
                     fcW, wt, 8192, 1024, 0L, 0L);
  hipLaunchKernelGGL(transpose_cvt_kernel, dim3(16, 4, 6), dim3(256), 0, stream,
                     W1, w1t, 1024, 256, (long)1027 * 256, (long)256 * 1024);
  hipLaunchKernelGGL(bucket_kernel, dim3(1), dim3(1024), 0, stream, cmd, idxlist, meta);
  hipLaunchKernelGGL(gemm_kernel, dim3(512), dim3(512), 0, stream, xb, wt, fcb, hbuf);
  hipLaunchKernelGGL(head_kernel, dim3(256, 6), dim3(256), 0, stream,
                     hbuf, w1t, W1, b1, W2, b2, ego, idxlist, meta, out);
}